// Round 9
// baseline (167.795 us; speedup 1.0000x reference)
//
#include <hip/hip_runtime.h>
#include <hip/hip_fp16.h>
#include <math.h>

#define N_PTS   65536
#define BATCH   2
#define TOTAL   (BATCH * N_PTS)   // 131072
#define NPACK_DW 16               // dwords per point, neighbor payload (64 B)
#define CPACK   12                // floats per point, center payload
#define EPSB    1e-5f

typedef float  f32x4  __attribute__((ext_vector_type(4)));
typedef _Float16 f16x8 __attribute__((ext_vector_type(8)));

static __device__ inline unsigned h2u(float a, float b) {
    __half2 h = __floats2half2_rn(a, b);
    union { __half2 h; unsigned u; } cv; cv.h = h; return cv.u;
}
static __device__ inline float2 u2f2(unsigned u) {
    union { unsigned u; __half2 h; } cv; cv.u = u; return __half22float2(cv.h);
}
static __device__ inline unsigned pk_max(unsigned a, unsigned b) {
    unsigned r; asm("v_pk_max_f16 %0, %1, %2" : "=v"(r) : "v"(a), "v"(b)); return r;
}
static __device__ inline unsigned pk_fma(unsigned a, unsigned b, unsigned c) {
    unsigned r; asm("v_pk_fma_f16 %0, %1, %2, %3" : "=v"(r) : "v"(a), "v"(b), "v"(c)); return r;
}
static __device__ inline unsigned pkrtz(float a, float b) {
    unsigned r; asm("v_cvt_pkrtz_f16_f32 %0, %1, %2" : "=v"(r) : "v"(a), "v"(b)); return r;
}

// ---------------------------------------------------------------------------
// Kernel 1: per-point precompute, 2 points/thread (weight ds_reads amortized).
//   packN[j] (64 B dwords):
//     0: h(x,y)  1: h(z,Mdot)  2-5: h(Bn0..7)
//     6-13: G int8 (offset-128), byte order [c0,c2,c1,c3] per dword
//     14: scale = max|G| (f32 bits)   15: pad
//   packC[j] (48 B) = { x,y,z,etadot | A'[0..7] }  (f32)
//   Block 0 additionally emits: fc16 (fc_W as f16 MFMA B-fragments) and
//   gateC[18] = { W0p[8], mW0[8], ms, mt } (gate constants, folded).
// ---------------------------------------------------------------------------
__global__ __launch_bounds__(128) void k1_precompute(
    const float* __restrict__ feats,   // [TOTAL][35]
    const float* __restrict__ pW,      // point_W  [10][8]
    const float* __restrict__ pBN,     // point_bn [4][8]
    const float* __restrict__ eW,      // eta_W    [32][8]
    const float* __restrict__ eBN,     // eta_bn   [4][8]
    const float* __restrict__ mW,      // mu_W     [32][8]
    const float* __restrict__ mBN,     // mu_bn    [4][8]
    const float* __restrict__ gW,      // gamma_W  [35][32]
    const float* __restrict__ gBN,     // gamma_bn [4][32]
    const float* __restrict__ mapW,    // map_W    [24]
    const float* __restrict__ mapBN,   // map_bn   [4]
    const float* __restrict__ fcW,     // [32][128]
    unsigned* __restrict__ packN,
    float* __restrict__ packC,
    unsigned* __restrict__ fc16,       // 512 frags x 16 B
    float* __restrict__ gateC)         // 18 f32
{
    __shared__ float sF[256 * 35];     // feats tile (256 points)
    __shared__ float sG[35 * 32];
    __shared__ float sE[32 * 8];
    __shared__ float sM[32 * 8];

    const int tid = threadIdx.x;       // 0..127
    const int base = blockIdx.x * 256;

    // ---- stage (coalesced) ---------------------------------------------
    {
        const float4* src4 = (const float4*)(feats + (size_t)base * 35);
        float4* dst4 = (float4*)sF;
        for (int i = tid; i < 2240; i += 128) dst4[i] = src4[i];
        for (int i = tid; i < 1120; i += 128) sG[i] = gW[i];
        sE[tid] = eW[tid]; sE[tid + 128] = eW[tid + 128];
        sM[tid] = mW[tid]; sM[tid + 128] = mW[tid + 128];
    }
    __syncthreads();

    const float* f0 = sF + tid * 35;          // rows tid, tid+128: bank-stride 3
    const float* f1 = sF + (tid + 128) * 35;

    // ---- G = f @ gamma_W for both points (weights read once) -----------
    float G[2][32];
#pragma unroll
    for (int q = 0; q < 32; ++q) { G[0][q] = 0.f; G[1][q] = 0.f; }
#pragma unroll 5
    for (int d = 0; d < 35; ++d) {
        const float fd0 = f0[d], fd1 = f1[d];
        const float4* w4 = (const float4*)(sG + d * 32);
#pragma unroll
        for (int q4 = 0; q4 < 8; ++q4) {
            const float4 w = w4[q4];
            G[0][q4 * 4 + 0] = fmaf(fd0, w.x, G[0][q4 * 4 + 0]);
            G[0][q4 * 4 + 1] = fmaf(fd0, w.y, G[0][q4 * 4 + 1]);
            G[0][q4 * 4 + 2] = fmaf(fd0, w.z, G[0][q4 * 4 + 2]);
            G[0][q4 * 4 + 3] = fmaf(fd0, w.w, G[0][q4 * 4 + 3]);
            G[1][q4 * 4 + 0] = fmaf(fd1, w.x, G[1][q4 * 4 + 0]);
            G[1][q4 * 4 + 1] = fmaf(fd1, w.y, G[1][q4 * 4 + 1]);
            G[1][q4 * 4 + 2] = fmaf(fd1, w.z, G[1][q4 * 4 + 2]);
            G[1][q4 * 4 + 3] = fmaf(fd1, w.w, G[1][q4 * 4 + 3]);
        }
    }

    // ---- eta / mu for both points ---------------------------------------
    float eta[2][8], mu[2][8];
#pragma unroll
    for (int q = 0; q < 8; ++q) { eta[0][q]=0.f; eta[1][q]=0.f; mu[0][q]=0.f; mu[1][q]=0.f; }
#pragma unroll 4
    for (int i = 0; i < 32; ++i) {
        const float fi0 = f0[3 + i], fi1 = f1[3 + i];
        const float4* e4 = (const float4*)(sE + i * 8);
        const float4* m4 = (const float4*)(sM + i * 8);
#pragma unroll
        for (int h = 0; h < 2; ++h) {
            const float4 we = e4[h], wm = m4[h];
#pragma unroll
            for (int b = 0; b < 4; ++b) {
                const float ew = (&we.x)[b], mw = (&wm.x)[b];
                eta[0][h*4+b] = fmaf(fi0, ew, eta[0][h*4+b]);
                eta[1][h*4+b] = fmaf(fi1, ew, eta[1][h*4+b]);
                mu[0][h*4+b]  = fmaf(fi0, mw, mu[0][h*4+b]);
                mu[1][h*4+b]  = fmaf(fi1, mw, mu[1][h*4+b]);
            }
        }
    }

    // ---- per-point epilogue ---------------------------------------------
#pragma unroll
    for (int pt = 0; pt < 2; ++pt) {
        const float* f = pt ? f1 : f0;
        const int j = base + tid + pt * 128;
        const float x = f[0], y = f[1], z = f[2];
        const float pp = x * x + y * y + z * z;

        float Gp[32];
#pragma unroll
        for (int q = 0; q < 32; ++q) {
            const float g = gBN[q], b = gBN[32 + q], m = gBN[64 + q], v = gBN[96 + q];
            const float s = g / sqrtf(v + EPSB);
            Gp[q] = fmaf(G[pt][q], s, b - m * s);
        }

        float etadot = 0.f, Mdot = 0.f;
#pragma unroll
        for (int q = 0; q < 8; ++q) {
            const float ge = eBN[q], be = eBN[8 + q], me = eBN[16 + q], ve = eBN[24 + q];
            const float se = ge / sqrtf(ve + EPSB);
            etadot = fmaf(fmaf(eta[pt][q], se, be - me * se), mapW[8 + q], etadot);
            const float gm = mBN[q], bm = mBN[8 + q], mm = mBN[16 + q], vm = mBN[24 + q];
            const float sm = gm / sqrtf(vm + EPSB);
            Mdot = fmaf(fmaf(mu[pt][q], sm, bm - mm * sm), mapW[16 + q], Mdot);
        }

        float Bnp[8], Ap[8];
#pragma unroll
        for (int q = 0; q < 8; ++q) {
            const float pw0 = pW[q];
            const float g = pBN[q], b = pBN[8 + q], m = pBN[16 + q], v = pBN[24 + q];
            const float s = g / sqrtf(v + EPSB);
            const float t = b - m * s;
            const float Braw = pp * pw0
                + x * (pW[32 + q] - pW[56 + q])
                + y * (pW[40 + q] - pW[64 + q])
                + z * (pW[48 + q] - pW[72 + q]);
            const float Araw = pp * pw0
                + x * (pW[8 + q]  + pW[56 + q])
                + y * (pW[16 + q] + pW[64 + q])
                + z * (pW[24 + q] + pW[72 + q]);
            Bnp[q] = Braw * s;
            Ap[q]  = fmaf(Araw, s, t);
        }

        // quant: bytes [c0, c2, c1, c3] so k2's (dw&0x00FF00FF) pairs are
        // channel-ordered
        float gmax = 0.f;
#pragma unroll
        for (int q = 0; q < 32; ++q) gmax = fmaxf(gmax, fabsf(Gp[q]));
        const float inv = (gmax > 0.f) ? (127.f / gmax) : 0.f;
        unsigned gq[8];
#pragma unroll
        for (int qd = 0; qd < 8; ++qd) {
            const unsigned u0 = (unsigned)((int)rintf(Gp[4*qd+0] * inv) + 128) & 0xffu;
            const unsigned u1 = (unsigned)((int)rintf(Gp[4*qd+1] * inv) + 128) & 0xffu;
            const unsigned u2 = (unsigned)((int)rintf(Gp[4*qd+2] * inv) + 128) & 0xffu;
            const unsigned u3 = (unsigned)((int)rintf(Gp[4*qd+3] * inv) + 128) & 0xffu;
            gq[qd] = u0 | (u2 << 8) | (u1 << 16) | (u3 << 24);
        }
        union { float f; unsigned u; } sc; sc.f = gmax;

        uint4* PN = (uint4*)(packN + (size_t)j * NPACK_DW);
        PN[0] = make_uint4(h2u(x, y), h2u(z, Mdot), h2u(Bnp[0], Bnp[1]), h2u(Bnp[2], Bnp[3]));
        PN[1] = make_uint4(h2u(Bnp[4], Bnp[5]), h2u(Bnp[6], Bnp[7]), gq[0], gq[1]);
        PN[2] = make_uint4(gq[2], gq[3], gq[4], gq[5]);
        PN[3] = make_uint4(gq[6], gq[7], sc.u, 0u);

        float4* PC = (float4*)(packC + (size_t)j * CPACK);
        PC[0] = make_float4(x, y, z, etadot);
        PC[1] = make_float4(Ap[0], Ap[1], Ap[2], Ap[3]);
        PC[2] = make_float4(Ap[4], Ap[5], Ap[6], Ap[7]);
    }

    // ---- block 0: fc_W -> f16 fragments + folded gate constants ---------
    if (blockIdx.x == 0) {
        for (int fi = tid; fi < 512; fi += 128) {
            const int lm = fi & 15, nt = (fi >> 4) & 7, lq = fi >> 7;
            unsigned dws[4];
#pragma unroll
            for (int p = 0; p < 4; ++p) {
                const float a = fcW[(8 * lq + 2 * p)     * 128 + nt * 16 + lm];
                const float b = fcW[(8 * lq + 2 * p + 1) * 128 + nt * 16 + lm];
                dws[p] = h2u(a, b);
            }
            ((uint4*)fc16)[fi] = make_uint4(dws[0], dws[1], dws[2], dws[3]);
        }
        if (tid == 0) {
#pragma unroll
            for (int q = 0; q < 8; ++q) {
                const float g = pBN[q], v = pBN[24 + q];
                const float s = g / sqrtf(v + EPSB);
                gateC[q]     = 2.f * pW[q] * s;   // W0p
                gateC[8 + q] = mapW[q];           // mW0
            }
            const float g = mapBN[0], b = mapBN[1], m = mapBN[2], v = mapBN[3];
            const float ms = g / sqrtf(v + EPSB);
            gateC[16] = ms;
            gateC[17] = b - m * ms;
        }
    }
}

// ---------------------------------------------------------------------------
// Kernel 2 (fused): gather + gate + packed-f16 max-pool + f16 MFMA fc.
// 32 centers/block, 8 lanes/center, 2 gathers/lane. Dequant via the f16
// bit-trick: (dw & 0x00FF00FF)|0x64006400 == packed f16 (1024+u8).
// ---------------------------------------------------------------------------
__global__ __launch_bounds__(256) void k2_aggregate_fc(
    const int* __restrict__ idx,      // [TOTAL][16]
    const unsigned* __restrict__ packN,
    const float* __restrict__ packC,
    const unsigned* __restrict__ fc16,
    const float* __restrict__ gateC,
    float* __restrict__ out)          // [TOTAL][128]
{
    __shared__ __align__(16) unsigned short sPool[32 * 40];  // f16 pooled tile

    // ---- XCD-batch affinity remap (grid = 4096, 8 XCDs round-robin) ----
    const int bid  = blockIdx.x;
    const int xcd  = bid & 7, slot = bid >> 3;
    const int cb   = (xcd < 4) ? (slot * 4 + xcd)
                               : (2048 + slot * 4 + (xcd - 4));
    const int cbase = cb * 32;

    const int tid  = threadIdx.x;
    const int cl   = tid >> 3;        // local center 0..31
    const int ks   = tid & 7;
    const int c    = cbase + cl;
    const int lane = tid & 63;
    const int w    = tid >> 6;        // wave 0..3
    const int lm   = lane & 15, lq = lane >> 4;

    // ---- B fragments: preshuffled f16, 2x b128 --------------------------
    f16x8 bfrag[2];
#pragma unroll
    for (int ntj = 0; ntj < 2; ++ntj) {
        union { uint4 u4; f16x8 v; } cv;
        cv.u4 = ((const uint4*)fc16)[(lq * 8 + 2 * w + ntj) * 16 + lm];
        bfrag[ntj] = cv.v;
    }

    // ---- gate constants (uniform scalar loads) --------------------------
    const float ms = gateC[16], mt = gateC[17];
    float W0p[8], mW0[8];
#pragma unroll
    for (int q = 0; q < 8; ++q) { W0p[q] = gateC[q]; mW0[q] = gateC[8 + q]; }

    const float4* PC = (const float4*)(packC + (size_t)c * CPACK);
    const float4 c0 = PC[0], c1 = PC[1], c2 = PC[2];
    const float px = c0.x, py = c0.y, pz = c0.z, etadot = c0.w;
    const float Ap[8] = { c1.x, c1.y, c1.z, c1.w, c2.x, c2.y, c2.z, c2.w };

    const int2 ib2 = ((const int2*)idx)[c * 8 + ks];
    const int bbase = c & ~(N_PTS - 1);

    unsigned o16[16];
#pragma unroll
    for (int q = 0; q < 16; ++q) o16[q] = 0xFC00FC00u;   // (-inf, -inf)

    const uint4* P0 = (const uint4*)(packN + (size_t)(bbase + ib2.x) * NPACK_DW);
    const uint4* P1 = (const uint4*)(packN + (size_t)(bbase + ib2.y) * NPACK_DW);
    uint4 n0[4] = { P0[0], P0[1], P0[2], P0[3] };
    uint4 n1[4] = { P1[0], P1[1], P1[2], P1[3] };

#pragma unroll
    for (int k = 0; k < 2; ++k) {
        const uint4* N = k ? n1 : n0;
        const float2 xy = u2f2(N[0].x), zM = u2f2(N[0].y);
        const float dot3 = px * xy.x + py * xy.y + pz * zM.x;

        const unsigned bn[4] = { N[0].z, N[0].w, N[1].x, N[1].y };
        float pd = 0.f;
#pragma unroll
        for (int q = 0; q < 4; ++q) {
            const float2 bn2 = u2f2(bn[q]);
            const float u0 = Ap[2 * q]     + bn2.x - dot3 * W0p[2 * q];
            const float u1 = Ap[2 * q + 1] + bn2.y - dot3 * W0p[2 * q + 1];
            pd = fmaf(fmaxf(u0, 0.f), mW0[2 * q], pd);
            pd = fmaf(fmaxf(u1, 0.f), mW0[2 * q + 1], pd);
        }
        float s = fmaf(pd + etadot + zM.y, ms, mt);
        s = fmaxf(s, 0.f);

        // dequant+gate: value = t*(1024+u8) - 1152*t  (u8 = q+128)
        union { unsigned u; float f; } sc; sc.u = N[3].z;
        const float t = s * sc.f * (1.f / 127.f);
        const unsigned t2 = pkrtz(t, t);
        const float d = -1152.f * t;
        const unsigned d2 = pkrtz(d, d);

        const unsigned gd[8] = { N[1].z, N[1].w, N[2].x, N[2].y,
                                 N[2].z, N[2].w, N[3].x, N[3].y };
#pragma unroll
        for (int qd = 0; qd < 8; ++qd) {
            const unsigned dwv = gd[qd];
            const unsigned lo = (dwv & 0x00FF00FFu) | 0x64006400u;
            const unsigned hi = ((dwv >> 8) & 0x00FF00FFu) | 0x64006400u;
            o16[2 * qd]     = pk_max(o16[2 * qd],     pk_fma(lo, t2, d2));
            o16[2 * qd + 1] = pk_max(o16[2 * qd + 1], pk_fma(hi, t2, d2));
        }
    }

    // ---- 3-level packed max reduce across the 8-lane group --------------
#pragma unroll
    for (int q = 0; q < 16; ++q) {
        unsigned v = o16[q];
        v = pk_max(v, (unsigned)__shfl_xor((int)v, 1));
        v = pk_max(v, (unsigned)__shfl_xor((int)v, 2));
        v = pk_max(v, (unsigned)__shfl_xor((int)v, 4));
        o16[q] = v;
    }

    // lane ks owns channels 4ks..4ks+3 (f16), one 8 B store ---------------
    {
        uint2 pk;
        pk.x = o16[2 * ks];
        pk.y = o16[2 * ks + 1];
        *(uint2*)(sPool + cl * 40 + ks * 4) = pk;
    }
    __syncthreads();

    // ---- fc via MFMA: D[32 x 32cols per wave] = pooled(32x32) @ fcW -----
    f32x4 acc[2][2];
#pragma unroll
    for (int a = 0; a < 2; ++a)
#pragma unroll
        for (int b = 0; b < 2; ++b)
            acc[a][b] = (f32x4){0.f, 0.f, 0.f, 0.f};

#pragma unroll
    for (int mtile = 0; mtile < 2; ++mtile) {
        const f16x8 afrag = *(const f16x8*)(sPool + (mtile * 16 + lm) * 40 + lq * 8);
#pragma unroll
        for (int ntj = 0; ntj < 2; ++ntj)
            acc[mtile][ntj] = __builtin_amdgcn_mfma_f32_16x16x32_f16(
                afrag, bfrag[ntj], acc[mtile][ntj], 0, 0, 0);
    }

#pragma unroll
    for (int mtile = 0; mtile < 2; ++mtile)
#pragma unroll
        for (int ntj = 0; ntj < 2; ++ntj) {
            const int nt = 2 * w + ntj;
#pragma unroll
            for (int r = 0; r < 4; ++r)
                __builtin_nontemporal_store(acc[mtile][ntj][r],
                    &out[(size_t)(cbase + mtile * 16 + lq * 4 + r) * 128 + nt * 16 + lm]);
        }
}

// ---------------------------------------------------------------------------
extern "C" void kernel_launch(void* const* d_in, const int* in_sizes, int n_in,
                              void* d_out, int out_size, void* d_ws, size_t ws_size,
                              hipStream_t stream) {
    const float* feats    = (const float*)d_in[0];
    const int*   idx      = (const int*)  d_in[1];
    const float* point_W  = (const float*)d_in[2];
    const float* point_bn = (const float*)d_in[3];
    const float* eta_W    = (const float*)d_in[4];
    const float* eta_bn   = (const float*)d_in[5];
    const float* mu_W     = (const float*)d_in[6];
    const float* mu_bn    = (const float*)d_in[7];
    const float* gamma_W  = (const float*)d_in[8];
    const float* gamma_bn = (const float*)d_in[9];
    const float* map_W    = (const float*)d_in[10];
    const float* map_bn   = (const float*)d_in[11];
    const float* fc_W     = (const float*)d_in[12];
    float* out = (float*)d_out;

    unsigned* packN = (unsigned*)d_ws;                            // 8 MB
    float*    packC = (float*)(packN + (size_t)TOTAL * NPACK_DW); // 6 MB
    unsigned* fc16  = (unsigned*)(packC + (size_t)TOTAL * CPACK); // 8 KB
    float*    gateC = (float*)(fc16 + 2048);                      // 72 B

    hipLaunchKernelGGL(k1_precompute, dim3(TOTAL / 256), dim3(128), 0, stream,
                       feats, point_W, point_bn, eta_W, eta_bn, mu_W, mu_bn,
                       gamma_W, gamma_bn, map_W, map_bn, fc_W,
                       packN, packC, fc16, gateC);
    hipLaunchKernelGGL(k2_aggregate_fc, dim3(TOTAL / 32), dim3(256), 0, stream,
                       idx, packN, packC, fc16, gateC, out);
}